// Round 1
// 117.443 us; speedup vs baseline: 1.0078x; 1.0078x over previous
//
#include <hip/hip_runtime.h>

#define NT 10          // trees
#define NL 16          // leaves per tree
#define NN 31          // nodes per tree
#define DD 256         // hidden dim
#define G4 1024        // 4*D gates
#define NNODES (NT*NN) // 310
#define NPATH (NT*NL)  // 160
#define NB 4096

__device__ __forceinline__ float sigf(float x)   { return 1.0f / (1.0f + __expf(-x)); }
__device__ __forceinline__ float tanh_f(float x) { return 2.0f / (1.0f + __expf(-2.0f*x)) - 1.0f; }

// ---------------------------------------------------------------------------
// K1: nodeproj. xg[n][j] = emb[n].Wih[j] + bih[j] + bhh[j]
// 256 blocks = (mt 0..15 [20 nodes]) x (nt 0..15 [64 W rows]). Proven ~3 us.
// Plain stores; the launch boundary publishes xg to the step kernels.
// ---------------------------------------------------------------------------
__global__ __launch_bounds__(256) void k_nodeproj(
    const float* __restrict__ emb, const float* __restrict__ Wih,
    const float* __restrict__ bih, const float* __restrict__ bhh,
    float* __restrict__ xg)
{
    __shared__ float smem[20 * 260 + 20 * 4 * 64];
    float4* es4 = (float4*)smem;
    float*  ps  = smem + 20 * 260;

    const int tid = threadIdx.x;
    const int nt  = blockIdx.x & 15;
    const int mt  = blockIdx.x >> 4;
    const int kq  = tid >> 6;
    const int w   = tid & 63;

    const float4* W4 = (const float4*)Wih + (size_t)(nt * 64 + w) * 64 + kq * 16;
    float4 wr[16];
    #pragma unroll
    for (int j = 0; j < 16; ++j) wr[j] = W4[j];

    const float4* emb4 = (const float4*)emb;
    #pragma unroll
    for (int r = 0; r < 5; ++r) {
        int idx = tid + 256 * r;                  // 0..1279
        int m = idx >> 6, q = idx & 63;
        int n = mt * 20 + m;
        es4[m * 65 + q] = (n < NNODES) ? emb4[(size_t)n * 64 + q]
                                       : make_float4(0.f, 0.f, 0.f, 0.f);
    }
    __syncthreads();

    float acc[20];
    #pragma unroll
    for (int m = 0; m < 20; ++m) acc[m] = 0.f;
    #pragma unroll
    for (int j = 0; j < 16; ++j) {
        float4 wv = wr[j];
        #pragma unroll
        for (int m = 0; m < 20; ++m) {
            float4 h = es4[m * 65 + kq * 16 + j];
            acc[m] = fmaf(wv.x, h.x, fmaf(wv.y, h.y,
                     fmaf(wv.z, h.z, fmaf(wv.w, h.w, acc[m]))));
        }
    }
    #pragma unroll
    for (int m = 0; m < 20; ++m) ps[(m * 4 + kq) * 64 + w] = acc[m];
    __syncthreads();

    const int nl   = tid & 63;
    const int msub = tid >> 6;
    const int j    = nt * 64 + nl;
    const float bsum = bih[j] + bhh[j];
    #pragma unroll
    for (int r = 0; r < 5; ++r) {
        int m = msub * 5 + r;
        int n = mt * 20 + m;
        float s = ps[(m * 4 + 0) * 64 + nl] + ps[(m * 4 + 1) * 64 + nl]
                + ps[(m * 4 + 2) * 64 + nl] + ps[(m * 4 + 3) * 64 + nl];
        if (n < NNODES) xg[(size_t)n * G4 + j] = s + bsum;
    }
}

// ---------------------------------------------------------------------------
// K2..K5: tree-structured LSTM step S (S=1..4), one launch per step.
//
// Key structure: the 160 leaf paths share tree prefixes, so the LSTM state
// after step s has only 10*2^s distinct rows. Step S consumes L = 2^(S-1)
// distinct h/c rows per tree and produces 2L rows. Cross-block publication
// of h/c happens at the LAUNCH BOUNDARY (plain stores) — this replaces the
// previous in-kernel MALL flag barrier that cost ~13 us per round.
//
// Grid: 160 blocks = 10 trees x 16 dtiles. Block (t,dt) owns 16 d-cols
// (64 W_hh rows = 4 gates x 16 cols) register-stationary; 256 threads split
// the 256-dim reduction into 4 quarters (kq), partials summed via LDS.
// For S=1, h0/c0 are computed in-block from the xg root row (h(-1)=c(-1)=0),
// so the first launch needs no h input at all.
// ---------------------------------------------------------------------------
template<int S>
__global__ __launch_bounds__(256) void k_step(
    const float* __restrict__ xg, const float* __restrict__ Whh,
    const float* __restrict__ hprev, const float* __restrict__ cprev,
    float* __restrict__ hout, float* __restrict__ cout)
{
    constexpr int L = 1 << (S - 1);        // distinct input rows per tree
    __shared__ float hs [L * DD];          // input h rows (full 256 width)
    __shared__ float ps [L * DD];          // GEMM partials (4 quarters x 64)
    __shared__ float csl[L * 16];          // input c rows, this block's d-slice

    const int tid  = threadIdx.x;
    const int t    = blockIdx.x >> 4;      // tree
    const int dt   = blockIdx.x & 15;      // d-tile (16 cols)
    const int kq   = tid >> 6;             // reduction quarter
    const int w    = tid & 63;             // W_hh row within tile
    const int gate = w >> 4;
    const int col  = w & 15;

    // W_hh quarter-rows -> registers (stationary for all L row-GEMMs)
    const float4* W4 = (const float4*)Whh
        + (size_t)(gate * DD + dt * 16 + col) * 64 + kq * 16;
    float4 wreg[16];
    #pragma unroll
    for (int j = 0; j < 16; ++j) wreg[j] = W4[j];

    if constexpr (S == 1) {
        // h0/c0 from the root xg row; f-gate irrelevant (c(-1)=0).
        const float* xr = xg + (size_t)(t * NN) * G4;
        float xi = xr[tid], xgg = xr[512 + tid], xo = xr[768 + tid];
        float c0 = sigf(xi) * tanh_f(xgg);
        float h0 = sigf(xo) * tanh_f(c0);
        hs[tid] = h0;
        if ((tid >> 4) == dt) csl[tid & 15] = c0;
    } else {
        #pragma unroll
        for (int rr = 0; rr < L; ++rr)
            hs[rr * DD + tid] = hprev[(size_t)(t * L + rr) * DD + tid];
        if (tid < L * 16)
            csl[tid] = cprev[(size_t)(t * L + (tid >> 4)) * DD
                             + dt * 16 + (tid & 15)];
    }
    __syncthreads();

    // GEMM: acc[p] = <W_hh[row] quarter kq, h[p] quarter kq>
    const float4* hs4 = (const float4*)hs;
    float acc[L];
    #pragma unroll
    for (int p = 0; p < L; ++p) acc[p] = 0.f;
    #pragma unroll
    for (int j = 0; j < 16; ++j) {
        float4 wv = wreg[j];
        #pragma unroll
        for (int p = 0; p < L; ++p) {
            float4 h = hs4[p * 64 + kq * 16 + j];    // wave-uniform broadcast
            acc[p] = fmaf(wv.x, h.x, fmaf(wv.y, h.y,
                     fmaf(wv.z, h.z, fmaf(wv.w, h.w, acc[p]))));
        }
    }
    #pragma unroll
    for (int p = 0; p < L; ++p) ps[p * DD + kq * 64 + w] = acc[p];
    __syncthreads();

    // Epilogue: each input row p spawns 2 children (distinct x-gate rows,
    // shared h.W_hh). 32*L threads: (p, child, col).
    if (tid < 32 * L) {
        const int p    = tid >> 5;
        const int ch   = (tid >> 4) & 1;
        const int c2   = tid & 15;
        const int q    = p * 2 + ch;                 // child prefix in tree
        const int node = ((1 << S) - 1) + q;         // tree-local node id
        const float* xn = xg + (size_t)(t * NN + node) * G4 + dt * 16 + c2;

        float g0 = 0.f, g1 = 0.f, g2 = 0.f, g3 = 0.f;
        #pragma unroll
        for (int k = 0; k < 4; ++k) {
            const float* pp = ps + p * DD + k * 64;
            g0 += pp[ 0 + c2]; g1 += pp[16 + c2];
            g2 += pp[32 + c2]; g3 += pp[48 + c2];
        }
        float gi = g0 + xn[0];
        float gf = g1 + xn[256];
        float gg = g2 + xn[512];
        float go = g3 + xn[768];
        float cin = csl[p * 16 + c2];
        float cn  = sigf(gf) * cin + sigf(gi) * tanh_f(gg);
        float hn  = sigf(go) * tanh_f(cn);

        size_t orow = (size_t)(t * 2 * L + q);
        hout[orow * DD + dt * 16 + c2] = hn;
        if constexpr (S < 4) cout[orow * DD + dt * 16 + c2] = cn;
    }
}

// ---------------------------------------------------------------------------
// K6: scatter out[b,t,:] = h4[t*16 + argmax(cross[b,t,:]), :]
// One wave per (b,t) row (40960 waves): ballot -> leaf, float4 row copy.
// ---------------------------------------------------------------------------
__global__ __launch_bounds__(256) void k_scatter(
    const float* __restrict__ cross, const float* __restrict__ htab,
    float* __restrict__ out)
{
    const int tid  = threadIdx.x;
    const int wave = tid >> 6;
    const int lane = tid & 63;
    const int r = blockIdx.x * 4 + wave;     // 0..40959 = b*10 + t
    const int b = r / NT;
    const int t = r - b * NT;

    float v = 0.f;
    if (lane < NL) v = cross[(size_t)b * (NT * NL) + t * NL + lane];
    unsigned long long m = __ballot(v > 0.5f);
    int leaf = m ? (int)__builtin_ctzll(m) : 0;
    int p = t * NL + leaf;

    const float4* h4 = (const float4*)htab;
    float4* o4 = (float4*)out;
    o4[(size_t)r * 64 + lane] = h4[(size_t)p * 64 + lane];
}

// ---------------------------------------------------------------------------
extern "C" void kernel_launch(void* const* d_in, const int* in_sizes, int n_in,
                              void* d_out, int out_size, void* d_ws, size_t ws_size,
                              hipStream_t stream)
{
    const float* cross = (const float*)d_in[0];
    const float* emb   = (const float*)d_in[1];
    const float* Wih   = (const float*)d_in[2];
    const float* Whh   = (const float*)d_in[3];
    const float* bih   = (const float*)d_in[4];
    const float* bhh   = (const float*)d_in[5];
    float* out = (float*)d_out;

    float* ws = (float*)d_ws;
    float* xg = ws;                          // 310*1024
    float* h1 = xg + (size_t)NNODES * G4;    // 20*256
    float* c1 = h1 + 20 * DD;
    float* h2 = c1 + 20 * DD;                // 40*256
    float* c2 = h2 + 40 * DD;
    float* h3 = c2 + 40 * DD;                // 80*256
    float* c3 = h3 + 80 * DD;
    float* h4 = c3 + 80 * DD;                // 160*256 (c4 never needed)

    hipLaunchKernelGGL(k_nodeproj, dim3(256), dim3(256), 0, stream,
                       emb, Wih, bih, bhh, xg);
    hipLaunchKernelGGL(HIP_KERNEL_NAME(k_step<1>), dim3(160), dim3(256), 0, stream,
                       xg, Whh, (const float*)nullptr, (const float*)nullptr, h1, c1);
    hipLaunchKernelGGL(HIP_KERNEL_NAME(k_step<2>), dim3(160), dim3(256), 0, stream,
                       xg, Whh, h1, c1, h2, c2);
    hipLaunchKernelGGL(HIP_KERNEL_NAME(k_step<3>), dim3(160), dim3(256), 0, stream,
                       xg, Whh, h2, c2, h3, c3);
    hipLaunchKernelGGL(HIP_KERNEL_NAME(k_step<4>), dim3(160), dim3(256), 0, stream,
                       xg, Whh, h3, c3, h4, (float*)nullptr);
    hipLaunchKernelGGL(k_scatter, dim3(10240), dim3(256), 0, stream,
                       cross, h4, out);
}

// Round 2
// 111.765 us; speedup vs baseline: 1.0590x; 1.0508x over previous
//
#include <hip/hip_runtime.h>

#define NT 10          // trees
#define NL 16          // leaves per tree
#define NN 31          // nodes per tree
#define DD 256         // hidden dim
#define G4 1024        // 4*D gates
#define NNODES (NT*NN) // 310
#define NPATH (NT*NL)  // 160
#define NB 4096

// Monotone per-(step,tree) arrival counters (zero-init at load; survive ws
// poison — they live in __device__ space; +16 per launch each). Base is read
// at kernel entry from the LAST step's flag, which cannot advance until every
// block of the tree has passed the earlier barriers (hence entered and read
// its own base) — so targets are launch-generation-free and replay-safe.
// 128 B stride per tree to keep flag lines independent.
__device__ unsigned g_tf[3][NT][32];

__device__ __forceinline__ float sigf(float x)   { return 1.0f / (1.0f + __expf(-x)); }
__device__ __forceinline__ float tanh_f(float x) { return 2.0f / (1.0f + __expf(-2.0f*x)) - 1.0f; }

__device__ __forceinline__ void co_store(float* p, float v) {
    union { float f; unsigned u; } c; c.f = v;
    __hip_atomic_store((unsigned*)p, c.u, __ATOMIC_RELAXED, __HIP_MEMORY_SCOPE_AGENT);
}

// ---------------------------------------------------------------------------
// K1: nodeproj. xg[n][j] = emb[n].Wih[j] + bih[j] + bhh[j]
// 256 blocks = (mt 0..15 [20 nodes]) x (nt 0..15 [64 W rows]). Proven ~3 us.
// Plain stores; the launch boundary publishes xg to K2.
// ---------------------------------------------------------------------------
__global__ __launch_bounds__(256) void k_nodeproj(
    const float* __restrict__ emb, const float* __restrict__ Wih,
    const float* __restrict__ bih, const float* __restrict__ bhh,
    float* __restrict__ xg)
{
    __shared__ float smem[20 * 260 + 20 * 4 * 64];
    float4* es4 = (float4*)smem;
    float*  ps  = smem + 20 * 260;

    const int tid = threadIdx.x;
    const int nt  = blockIdx.x & 15;
    const int mt  = blockIdx.x >> 4;
    const int kq  = tid >> 6;
    const int w   = tid & 63;

    const float4* W4 = (const float4*)Wih + (size_t)(nt * 64 + w) * 64 + kq * 16;
    float4 wr[16];
    #pragma unroll
    for (int j = 0; j < 16; ++j) wr[j] = W4[j];

    const float4* emb4 = (const float4*)emb;
    #pragma unroll
    for (int r = 0; r < 5; ++r) {
        int idx = tid + 256 * r;                  // 0..1279
        int m = idx >> 6, q = idx & 63;
        int n = mt * 20 + m;
        es4[m * 65 + q] = (n < NNODES) ? emb4[(size_t)n * 64 + q]
                                       : make_float4(0.f, 0.f, 0.f, 0.f);
    }
    __syncthreads();

    float acc[20];
    #pragma unroll
    for (int m = 0; m < 20; ++m) acc[m] = 0.f;
    #pragma unroll
    for (int j = 0; j < 16; ++j) {
        float4 wv = wr[j];
        #pragma unroll
        for (int m = 0; m < 20; ++m) {
            float4 h = es4[m * 65 + kq * 16 + j];
            acc[m] = fmaf(wv.x, h.x, fmaf(wv.y, h.y,
                     fmaf(wv.z, h.z, fmaf(wv.w, h.w, acc[m]))));
        }
    }
    #pragma unroll
    for (int m = 0; m < 20; ++m) ps[(m * 4 + kq) * 64 + w] = acc[m];
    __syncthreads();

    const int nl   = tid & 63;
    const int msub = tid >> 6;
    const int j    = nt * 64 + nl;
    const float bsum = bih[j] + bhh[j];
    #pragma unroll
    for (int r = 0; r < 5; ++r) {
        int m = msub * 5 + r;
        int n = mt * 20 + m;
        float s = ps[(m * 4 + 0) * 64 + nl] + ps[(m * 4 + 1) * 64 + nl]
                + ps[(m * 4 + 2) * 64 + nl] + ps[(m * 4 + 3) * 64 + nl];
        if (n < NNODES) xg[(size_t)n * G4 + j] = s + bsum;
    }
}

// ---------------------------------------------------------------------------
// K2: all 4 LSTM steps, TREE-structured, one launch.
//
// The 160 leaf paths share tree prefixes: state after step s has only
// 10*2^s distinct rows; step s consumes 2^(s-1) rows per tree and spawns
// 2^s. Total 150 row-GEMMs vs 640 in the path-structured version.
//
// Grid: 160 blocks = 10 trees x 16 dtiles, all co-resident (160 < 256 CUs).
// Block (t,dt) owns 16 d-cols (64 W_hh rows = 4 gates x 16 cols) register-
// stationary for all steps. h exchange between the 16 blocks of a tree goes
// through ws (MALL) with the proven relaxed co_store + __syncthreads-drain +
// tid0 fetch_add protocol; consumers: wave0 polls with s_sleep backoff, then
// __syncthreads releases the block (16 pollers/line, not 64 — keeps the
// producers' RMWs from being starved). c never crosses blocks (d-local):
// it lives in LDS ping-pong buffers. Root step is elementwise (no GEMM).
// ---------------------------------------------------------------------------
__global__ __launch_bounds__(256) void k_treesteps(
    const float* __restrict__ xg, const float* __restrict__ Whh,
    float* __restrict__ h1g, float* __restrict__ h2g,
    float* __restrict__ h3g, float* __restrict__ h4g)
{
    __shared__ float hs[8 * DD];       // input h rows (full width), max L=8
    __shared__ float ps[8 * DD];       // GEMM partials (4 quarters x 64)
    __shared__ float cbuf[2][8 * 16];  // c ping-pong, this block's 16 cols

    const int tid  = threadIdx.x;
    const int t    = blockIdx.x >> 4;  // tree
    const int dt   = blockIdx.x & 15;  // d-tile
    const int kq   = tid >> 6;         // reduction quarter
    const int w    = tid & 63;
    const int gate = w >> 4;
    const int col  = w & 15;

    // Stable pre-arrival base for all three barrier targets (see decl note).
    const unsigned base = __hip_atomic_load(&g_tf[2][t][0],
        __ATOMIC_RELAXED, __HIP_MEMORY_SCOPE_AGENT);

    // ---- Entry prefetch #1: W_hh quarter-rows (stationary all 4 steps)
    const float4* W4 = (const float4*)Whh
        + (size_t)(gate * DD + dt * 16 + col) * 64 + kq * 16;
    float4 wreg[16];
    #pragma unroll
    for (int j = 0; j < 16; ++j) wreg[j] = W4[j];

    // ---- Entry prefetch #2: xn gate biases for steps 1..4.
    // Step s epilogue thread tid (tid < 32*2^(s-1)) handles child q=tid>>4,
    // node (1<<s)-1+q, col dt*16+(tid&15), all 4 gates.
    float xnv[4][4];
    #pragma unroll
    for (int s = 1; s <= 4; ++s) {
        xnv[s-1][0] = 0.f; xnv[s-1][1] = 0.f;
        xnv[s-1][2] = 0.f; xnv[s-1][3] = 0.f;
        if (tid < (32 << (s - 1))) {
            int node = (1 << s) - 1 + (tid >> 4);
            const float* xn = xg + (size_t)(t * NN + node) * G4 + dt * 16 + (tid & 15);
            xnv[s-1][0] = xn[0];
            xnv[s-1][1] = xn[256];
            xnv[s-1][2] = xn[512];
            xnv[s-1][3] = xn[768];
        }
    }

    // ---- Entry prefetch #3 + root step (elementwise, full width, no GEMM)
    {
        const float* xr = xg + (size_t)(t * NN) * G4;
        float r_i = xr[tid], r_g = xr[512 + tid], r_o = xr[768 + tid];
        float c0 = sigf(r_i) * tanh_f(r_g);        // h(-1)=c(-1)=0
        float h0 = sigf(r_o) * tanh_f(c0);
        hs[tid] = h0;                              // row 0, full width
        if ((tid >> 4) == dt) cbuf[0][tid & 15] = c0;
    }
    __syncthreads();

    float* hout[3] = { h1g, h2g, h3g };
    const float* hin[3] = { h1g, h2g, h3g };

    #pragma unroll
    for (int s = 1; s <= 4; ++s) {
        const int L = 1 << (s - 1);                // input rows per tree

        if (s > 1) {
            // wait for step-(s-1) h rows from all 16 blocks of this tree
            if (tid < 64) {
                const unsigned tgt = base + 16u;
                while (__hip_atomic_load(&g_tf[s - 2][t][0],
                        __ATOMIC_RELAXED, __HIP_MEMORY_SCOPE_AGENT) < tgt)
                    __builtin_amdgcn_s_sleep(2);
            }
            __syncthreads();
            // stage L rows x 256 floats = L*128 u64, linear copy into hs
            const unsigned long long* src =
                (const unsigned long long*)(hin[s - 2] + (size_t)t * L * DD);
            unsigned long long raw[4];
            #pragma unroll
            for (int r = 0; r < L / 2; ++r)
                raw[r] = __hip_atomic_load(src + tid + 256 * r,
                    __ATOMIC_RELAXED, __HIP_MEMORY_SCOPE_AGENT);
            float2* hs2 = (float2*)hs;
            #pragma unroll
            for (int r = 0; r < L / 2; ++r) {
                union { unsigned long long u; float2 f; } cv; cv.u = raw[r];
                hs2[tid + 256 * r] = cv.f;
            }
            __syncthreads();
        }

        // GEMM: acc[p] = <W_hh[row] quarter kq, h[p] quarter kq>
        const float4* hs4 = (const float4*)hs;
        float acc[8];
        #pragma unroll
        for (int p = 0; p < 8; ++p) acc[p] = 0.f;
        #pragma unroll
        for (int j = 0; j < 16; ++j) {
            float4 wv = wreg[j];
            #pragma unroll
            for (int p = 0; p < L; ++p) {
                float4 h = hs4[p * 64 + kq * 16 + j];     // uniform broadcast
                acc[p] = fmaf(wv.x, h.x, fmaf(wv.y, h.y,
                         fmaf(wv.z, h.z, fmaf(wv.w, h.w, acc[p]))));
            }
        }
        #pragma unroll
        for (int p = 0; p < L; ++p) ps[p * DD + kq * 64 + w] = acc[p];
        __syncthreads();

        // Epilogue: parent p spawns children q=2p,2p+1 (distinct x-gates,
        // shared h.W_hh). 32*L threads: (p, child, col).
        if (tid < 32 * L) {
            const int p  = tid >> 5;
            const int c2 = tid & 15;
            const int q  = tid >> 4;               // child prefix, 0..2L-1
            float g0 = 0.f, g1 = 0.f, g2 = 0.f, g3 = 0.f;
            #pragma unroll
            for (int k = 0; k < 4; ++k) {
                const float* pp = ps + p * DD + k * 64;
                g0 += pp[ 0 + c2]; g1 += pp[16 + c2];
                g2 += pp[32 + c2]; g3 += pp[48 + c2];
            }
            float gi = g0 + xnv[s - 1][0];
            float gf = g1 + xnv[s - 1][1];
            float gg = g2 + xnv[s - 1][2];
            float go = g3 + xnv[s - 1][3];
            float cin = cbuf[(s - 1) & 1][p * 16 + c2];
            float cn  = sigf(gf) * cin + sigf(gi) * tanh_f(gg);
            float hn  = sigf(go) * tanh_f(cn);
            if (s < 4) {
                cbuf[s & 1][q * 16 + c2] = cn;
                co_store(hout[s - 1] + (size_t)(t * 2 * L + q) * DD
                                     + dt * 16 + c2, hn);
            } else {
                // launch boundary publishes h4 to the scatter kernel
                h4g[(size_t)(t * NL + q) * DD + dt * 16 + c2] = hn;
            }
        }

        if (s < 4) {
            // drain this block's coherent h stores, then signal arrival
            __syncthreads();
            if (tid == 0)
                __hip_atomic_fetch_add(&g_tf[s - 1][t][0], 1u,
                    __ATOMIC_RELAXED, __HIP_MEMORY_SCOPE_AGENT);
        }
    }
}

// ---------------------------------------------------------------------------
// K3: scatter out[b,t,:] = h4[t*16 + argmax(cross[b,t,:]), :]
// One wave per (b,t) row (40960 waves): ballot -> leaf, float4 row copy.
// ---------------------------------------------------------------------------
__global__ __launch_bounds__(256) void k_scatter(
    const float* __restrict__ cross, const float* __restrict__ htab,
    float* __restrict__ out)
{
    const int tid  = threadIdx.x;
    const int wave = tid >> 6;
    const int lane = tid & 63;
    const int r = blockIdx.x * 4 + wave;     // 0..40959 = b*10 + t
    const int b = r / NT;
    const int t = r - b * NT;

    float v = 0.f;
    if (lane < NL) v = cross[(size_t)b * (NT * NL) + t * NL + lane];
    unsigned long long m = __ballot(v > 0.5f);
    int leaf = m ? (int)__builtin_ctzll(m) : 0;
    int p = t * NL + leaf;

    const float4* h4 = (const float4*)htab;
    float4* o4 = (float4*)out;
    o4[(size_t)r * 64 + lane] = h4[(size_t)p * 64 + lane];
}

// ---------------------------------------------------------------------------
extern "C" void kernel_launch(void* const* d_in, const int* in_sizes, int n_in,
                              void* d_out, int out_size, void* d_ws, size_t ws_size,
                              hipStream_t stream)
{
    const float* cross = (const float*)d_in[0];
    const float* emb   = (const float*)d_in[1];
    const float* Wih   = (const float*)d_in[2];
    const float* Whh   = (const float*)d_in[3];
    const float* bih   = (const float*)d_in[4];
    const float* bhh   = (const float*)d_in[5];
    float* out = (float*)d_out;

    float* ws = (float*)d_ws;
    float* xg = ws;                          // 310*1024
    float* h1 = xg + (size_t)NNODES * G4;    // 20*256
    float* h2 = h1 + 20 * DD;                // 40*256
    float* h3 = h2 + 40 * DD;                // 80*256
    float* h4 = h3 + 80 * DD;                // 160*256

    hipLaunchKernelGGL(k_nodeproj, dim3(256), dim3(256), 0, stream,
                       emb, Wih, bih, bhh, xg);
    hipLaunchKernelGGL(k_treesteps, dim3(160), dim3(256), 0, stream,
                       xg, Whh, h1, h2, h3, h4);
    hipLaunchKernelGGL(k_scatter, dim3(10240), dim3(256), 0, stream,
                       cross, h4, out);
}